// Round 6
// baseline (64.316 us; speedup 1.0000x reference)
//
#include <hip/hip_runtime.h>

// YOLO layer decode: (B, nA*(nC+5), g, g) f32 -> (B, nA*g*g, nC+5) f32
// B=64, nA=3, nC=80, g=52, stride = img_dim/g = 8.
//
// R6 = R4 structure (batched loads, load-side math, one barrier, NT stores)
// with TS 64->48: LDS 22.0->16.3 KB so 8 blocks/CU hit the 32-wave/CU cap
// (100% theoretical occupancy, was 62% measured). Goal: more outstanding
// requests to fill fabric bubbles. 2704 = 48*56 + 16 (one 16-wide tail tile).

#define G_     52
#define S_     2704                  // 52*52
#define NA_    3
#define C_     85                    // nC + 5
#define B_     64
#define TS_    48                    // spatial positions per full tile
#define NQ_    (TS_ / 4)             // 12 float4 quads per channel
#define ITEMS_ (C_ * NQ_)            // 1020 float4 items per full tile
#define NTILES 57                    // 56 full + 1 tail (16 positions)

#define LOG2E_ 1.44269504088896340736f

typedef float f32x4 __attribute__((ext_vector_type(4)));

__device__ __forceinline__ float fast_sigmoid(float v) {
    // 1/(1+e^-v) = rcp(1 + 2^(-v*log2e)); v_exp_f32 + v_rcp_f32, ~1 ulp each
    float e = __builtin_amdgcn_exp2f(-LOG2E_ * v);
    return __builtin_amdgcn_rcpf(1.0f + e);
}

__global__ __launch_bounds__(256) void yolo_decode_kernel(
    const float* __restrict__ x,
    const int*   __restrict__ img_dim_p,
    float*       __restrict__ out)
{
    __shared__ float lds[TS_ * C_];   // 16320 B -> 8 blocks/CU (wave-cap)

    const int tile = blockIdx.x;
    const int a    = blockIdx.y;
    const int b    = blockIdx.z;
    const int s0   = tile * TS_;
    const int tid  = threadIdx.x;

    // img_dim may arrive as int32 or float32 bits; disambiguate.
    int   bits = img_dim_p[0];
    float img  = (bits > 0 && bits < (1 << 20)) ? (float)bits
                                                : __int_as_float(bits);
    const float stride = img / (float)G_;   // 8.0

    // anchors (compile-time); (anchor/stride)*stride folds back exactly
    const float aw = (a == 0) ? 10.0f : (a == 1) ? 16.0f : 33.0f;
    const float ah = (a == 0) ? 13.0f : (a == 1) ? 30.0f : 23.0f;

    const float* inb = x + (size_t)(b * NA_ + a) * (size_t)(C_ * S_);

    if (tile != NTILES - 1) {
        // ---------- full tile: 48 positions, 1020 float4 items ----------
        // 4 iterations of 256 threads; last covers tid < 252.
        f32x4 r[4];
        int   c_[4], sq_[4];
        #pragma unroll
        for (int i = 0; i < 4; ++i) {
            const int t = tid + 256 * i;
            c_[i]  = t / NQ_;               // magic-mul div by 12
            sq_[i] = t - NQ_ * c_[i];
            if (i < 3 || tid < ITEMS_ - 768)
                r[i] = *reinterpret_cast<const f32x4*>(
                    inb + (size_t)c_[i] * S_ + s0 + 4 * sq_[i]);
        }
        #pragma unroll
        for (int i = 0; i < 4; ++i) {
            if (i < 3 || tid < ITEMS_ - 768) {
                const int c  = c_[i];       // near-wave-uniform
                const int sq = sq_[i];
                f32x4 v = r[i];
                if (c >= 4) {
                    #pragma unroll
                    for (int m = 0; m < 4; ++m) v[m] = fast_sigmoid(v[m]);
                } else if (c == 0) {
                    #pragma unroll
                    for (int m = 0; m < 4; ++m) {
                        const int sg = s0 + 4 * sq + m;
                        v[m] = (fast_sigmoid(v[m]) + (float)(sg % G_)) * stride;
                    }
                } else if (c == 1) {
                    #pragma unroll
                    for (int m = 0; m < 4; ++m) {
                        const int sg = s0 + 4 * sq + m;
                        v[m] = (fast_sigmoid(v[m]) + (float)(sg / G_)) * stride;
                    }
                } else if (c == 2) {
                    #pragma unroll
                    for (int m = 0; m < 4; ++m)
                        v[m] = __builtin_amdgcn_exp2f(LOG2E_ * v[m]) * aw;
                } else {  // c == 3
                    #pragma unroll
                    for (int m = 0; m < 4; ++m)
                        v[m] = __builtin_amdgcn_exp2f(LOG2E_ * v[m]) * ah;
                }
                const int base = 4 * sq * C_ + c;
                lds[base         ] = v[0];
                lds[base +     C_] = v[1];
                lds[base + 2 * C_] = v[2];
                lds[base + 3 * C_] = v[3];
            }
        }
    } else {
        // ---------- tail tile: 16 positions, 85*4 = 340 float4 items ----------
        for (int t = tid; t < C_ * 4; t += 256) {
            const int c  = t >> 2;
            const int sq = t & 3;
            f32x4 v = *reinterpret_cast<const f32x4*>(
                inb + (size_t)c * S_ + s0 + 4 * sq);
            if (c >= 4) {
                #pragma unroll
                for (int m = 0; m < 4; ++m) v[m] = fast_sigmoid(v[m]);
            } else if (c == 0) {
                #pragma unroll
                for (int m = 0; m < 4; ++m) {
                    const int sg = s0 + 4 * sq + m;
                    v[m] = (fast_sigmoid(v[m]) + (float)(sg % G_)) * stride;
                }
            } else if (c == 1) {
                #pragma unroll
                for (int m = 0; m < 4; ++m) {
                    const int sg = s0 + 4 * sq + m;
                    v[m] = (fast_sigmoid(v[m]) + (float)(sg / G_)) * stride;
                }
            } else if (c == 2) {
                #pragma unroll
                for (int m = 0; m < 4; ++m)
                    v[m] = __builtin_amdgcn_exp2f(LOG2E_ * v[m]) * aw;
            } else {
                #pragma unroll
                for (int m = 0; m < 4; ++m)
                    v[m] = __builtin_amdgcn_exp2f(LOG2E_ * v[m]) * ah;
            }
            const int base = 4 * sq * C_ + c;
            lds[base         ] = v[0];
            lds[base +     C_] = v[1];
            lds[base + 2 * C_] = v[2];
            lds[base + 3 * C_] = v[3];
        }
    }
    __syncthreads();

    // ---- store phase: pure copy, ds_read_b128 + nontemporal float4 store ----
    float* outb = out + ((size_t)(b * NA_ + a) * S_ + s0) * C_;

    if (tile != NTILES - 1) {
        #pragma unroll
        for (int i = 0; i < 4; ++i) {
            const int u = tid + 256 * i;    // 1020 float4s
            if (i < 3 || tid < ITEMS_ - 768) {
                const f32x4 v = *reinterpret_cast<const f32x4*>(&lds[4 * u]);
                __builtin_nontemporal_store(v, reinterpret_cast<f32x4*>(outb + 4 * u));
            }
        }
    } else {
        for (int u = tid; u < 340; u += 256) {
            const f32x4 v = *reinterpret_cast<const f32x4*>(&lds[4 * u]);
            __builtin_nontemporal_store(v, reinterpret_cast<f32x4*>(outb + 4 * u));
        }
    }
}

extern "C" void kernel_launch(void* const* d_in, const int* in_sizes, int n_in,
                              void* d_out, int out_size, void* d_ws, size_t ws_size,
                              hipStream_t stream)
{
    const float* x   = (const float*)d_in[0];
    const int*   img = (const int*)d_in[1];
    float*       out = (float*)d_out;

    dim3 grid(NTILES, NA_, B_);
    dim3 block(256);
    yolo_decode_kernel<<<grid, block, 0, stream>>>(x, img, out);
}